// Round 7
// baseline (827.482 us; speedup 1.0000x reference)
//
#include <hip/hip_runtime.h>
#include <hip/hip_bf16.h>

typedef unsigned short ushort_t;
typedef unsigned int uint_t;
typedef __attribute__((ext_vector_type(8))) short short8;
typedef __attribute__((ext_vector_type(4))) float float4v;

__device__ __forceinline__ float bf2f(ushort_t u) {
    union { uint_t i; float f; } c; c.i = ((uint_t)u) << 16; return c.f;
}
__device__ __forceinline__ ushort_t f2bf(float f) {
    union { float f; uint_t i; } c; c.f = f;
    uint_t x = c.i;
    uint_t r = x + 0x7fffu + ((x >> 16) & 1u);   // RNE
    return (ushort_t)(r >> 16);
}

// async global->LDS, 16B per lane; LDS dest = wave-uniform base + lane*16
__device__ __forceinline__ void gl_lds16(const void* g, void* l) {
    __builtin_amdgcn_global_load_lds(
        (const __attribute__((address_space(1))) void*)g,
        (__attribute__((address_space(3))) void*)l, 16, 0, 0);
}

__device__ __forceinline__ void stv(float* p, float v) { *p = v; }
__device__ __forceinline__ void stv(ushort_t* p, float v) { *p = f2bf(v); }

// generalized gather loads: su = row stride in 4B units, ou = 4B-unit offset
__device__ __forceinline__ float2 ld2g(const float* act, size_t row, int su, int ou, int t) {
    return ((const float2*)act)[row * su + ou + t];
}
__device__ __forceinline__ float2 ld2g(const ushort_t* act, size_t row, int su, int ou, int t) {
    uint_t u = ((const uint_t*)act)[row * su + ou + t];
    float2 r; r.x = bf2f((ushort_t)(u & 0xffffu)); r.y = bf2f((ushort_t)(u >> 16));
    return r;
}
__device__ __forceinline__ uint_t self_pack(const float* act, size_t row, int su, int ou, int t) {
    float2 s = ((const float2*)act)[row * su + ou + t];
    return ((uint_t)f2bf(s.y) << 16) | (uint_t)f2bf(s.x);
}
__device__ __forceinline__ uint_t self_pack(const ushort_t* act, size_t row, int su, int ou, int t) {
    return ((const uint_t*)act)[row * su + ou + t];
}

// ---------------- graph setup: counting sort by dst ----------------
__global__ __launch_bounds__(1024) void scan_kernel(
    const int* __restrict__ cnt, int* __restrict__ rowptr,
    int* __restrict__ cursor, float* __restrict__ deginv, int n) {
    __shared__ int sums[1024];
    const int t = threadIdx.x;
    const int per = (n + 1023) >> 10;
    const int b0 = t * per;
    int s = 0;
    for (int u = 0; u < per; u++) {
        int i = b0 + u;
        if (i < n) s += cnt[i];
    }
    sums[t] = s;
    __syncthreads();
    int x = s;
    for (int off = 1; off < 1024; off <<= 1) {
        int y = (t >= off) ? sums[t - off] : 0;
        __syncthreads();
        x += y;
        sums[t] = x;
        __syncthreads();
    }
    int run = x - s;   // exclusive prefix of this thread's chunk
    for (int u = 0; u < per; u++) {
        int i = b0 + u;
        if (i < n) {
            int v = cnt[i];
            rowptr[i] = run;
            cursor[i] = run;
            deginv[i] = 1.0f / (float)(v > 0 ? v : 1);
            run += v;
        }
    }
    if (t == 1023) rowptr[n] = x;
}

__global__ void scatter_kernel(const int* __restrict__ srcv, const int* __restrict__ dstv,
                               int* __restrict__ cursor, int* __restrict__ srcs_sorted, int E) {
    int e = blockIdx.x * 256 + threadIdx.x;
    if (e < E) {
        int p = atomicAdd(&cursor[dstv[e]], 1);
        srcs_sorted[p] = srcv[e];
    }
}

// ---------------- fused setup: w5 transposes + ws2 transpose + hist ----------------
struct W5 { const float* W0[5]; const float* W1[5]; };

__global__ __launch_bounds__(256) void setup_kernel(
    W5 wp, ushort_t* __restrict__ WT,
    const float* __restrict__ Ws2_0, const float* __restrict__ Ws2_1,
    ushort_t* __restrict__ WTs2, int Nout, int nbx,
    const int* __restrict__ dstv, int* __restrict__ cnt, int E) {
    __shared__ ushort_t tile[64][72];
    const int b = blockIdx.x;
    const int tid = threadIdx.x;
    if (b < 40) {
        // square layer (128x128) tile: WT[i][k] = bf16(W[k][i])
        const int bx = b & 1, by = (b >> 1) & 3, layer = b >> 3;
        const int i0 = bx * 64, k0 = by * 64;
        const float* W = (k0 < 128) ? (wp.W0[layer] + (size_t)k0 * 128)
                                    : (wp.W1[layer] + (size_t)(k0 - 128) * 128);
        ushort_t* WTb = WT + (size_t)layer * 128 * 256;
        const int li = tid & 63;
        const int kq = tid >> 6;
        const int gi = i0 + li;
        for (int k = kq; k < 64; k += 4)
            tile[li][k] = f2bf(W[(size_t)k * 128 + gi]);
        __syncthreads();
        for (int s = tid; s < 512; s += 256) {
            int r = s >> 3, ch = s & 7;
            *(short8*)(WTb + (size_t)(i0 + r) * 256 + k0 + ch * 8) = *(const short8*)&tile[r][ch * 8];
        }
    } else if (b < 40 + nbx * 4) {
        // s2 (Nout x 256) tile with tail guards
        const int vt = b - 40;
        const int bx = vt % nbx, by = vt / nbx;
        const int i0 = bx * 64, k0 = by * 64;
        const float* W = (k0 < 128) ? (Ws2_0 + (size_t)k0 * Nout)
                                    : (Ws2_1 + (size_t)(k0 - 128) * Nout);
        const int li = tid & 63;
        const int kq = tid >> 6;
        const int gi = i0 + li;
        const bool ok = gi < Nout;
        for (int k = kq; k < 64; k += 4) {
            float v = ok ? W[(size_t)k * Nout + gi] : 0.f;
            tile[li][k] = f2bf(v);
        }
        __syncthreads();
        for (int s = tid; s < 512; s += 256) {
            int r = s >> 3, ch = s & 7;
            int gi2 = i0 + r;
            if (gi2 < Nout)
                *(short8*)(WTs2 + (size_t)gi2 * 256 + k0 + ch * 8) = *(const short8*)&tile[r][ch * 8];
        }
    } else {
        // histogram
        int e = (b - 40 - nbx * 4) * 256 + tid;
        if (e < E) atomicAdd(&cnt[dstv[e]], 1);
    }
}

// ---------------- s-half aggregate (for s2's B operand) ----------------
// act = hbC [N][256] bf16; AcatS[n][0:128] = bf16(mean of s-half), [128:256] = self s-half
__global__ __launch_bounds__(256) void aggS_kernel(
    const ushort_t* __restrict__ act, const int* __restrict__ srcs,
    const int* __restrict__ rowptr, const float* __restrict__ deginv,
    ushort_t* __restrict__ AcatS, int N) {
    int node = blockIdx.x * 4 + (threadIdx.x >> 6);
    if (node >= N) return;
    int t = threadIdx.x & 63;
    const uint_t* A = (const uint_t*)act;
    int e0 = rowptr[node], e1 = rowptr[node + 1];
    float sx = 0.f, sy = 0.f;
    int e = e0;
    for (; e + 4 <= e1; e += 4) {
        size_t r0 = (size_t)srcs[e] * 128,     r1 = (size_t)srcs[e + 1] * 128;
        size_t r2 = (size_t)srcs[e + 2] * 128, r3 = (size_t)srcs[e + 3] * 128;
        uint_t us0 = A[r0 + 64 + t], us1 = A[r1 + 64 + t];
        uint_t us2 = A[r2 + 64 + t], us3 = A[r3 + 64 + t];
        sx += bf2f((ushort_t)(us0 & 0xffffu)) + bf2f((ushort_t)(us1 & 0xffffu))
            + bf2f((ushort_t)(us2 & 0xffffu)) + bf2f((ushort_t)(us3 & 0xffffu));
        sy += bf2f((ushort_t)(us0 >> 16))     + bf2f((ushort_t)(us1 >> 16))
            + bf2f((ushort_t)(us2 >> 16))     + bf2f((ushort_t)(us3 >> 16));
    }
    for (; e < e1; e++) {
        size_t r0 = (size_t)srcs[e] * 128;
        uint_t us0 = A[r0 + 64 + t];
        sx += bf2f((ushort_t)(us0 & 0xffffu));
        sy += bf2f((ushort_t)(us0 >> 16));
    }
    float dinv = deginv[node];
    size_t rb = (size_t)node * 128;
    uint_t ss = A[rb + 64 + t];
    ((uint_t*)AcatS)[rb + t]      = ((uint_t)f2bf(sy * dinv) << 16) | (uint_t)f2bf(sx * dinv);
    ((uint_t*)AcatS)[rb + 64 + t] = ss;
}

// ---------------- NT GEMM tile body (R4-proven, used by s2) ----------------
template <bool BIAS_I, int TM, typename TOUT>
__device__ __forceinline__ void gemm_tile_body(
    char* smem, int pid_m, int pid_n,
    const ushort_t* __restrict__ A, const ushort_t* __restrict__ B,
    const float* __restrict__ bias, const float* __restrict__ bias2, int jsplit,
    TOUT* __restrict__ C, int rowsA, int rowsB) {
    constexpr int IMN = TM / 32;               // A-fragments per wave (4 or 2)
    constexpr int NLD = IMN + 4;               // VMEM insts per stage per wave
    constexpr int ABYTES = TM * 128;           // A tile: TM x 64 bf16
    constexpr int BBYTES = 128 * 128;          // B tile: 128 x 64 bf16

    const int i0 = pid_m * TM;
    const int j0 = pid_n * 128;

    const int tid  = threadIdx.x;
    const int lane = tid & 63;
    const int wid  = tid >> 6;
    const int wm = wid >> 1, wn = wid & 1;
    const int r16 = lane & 15, quad = lane >> 4;
    const int rsub = lane >> 3;              // row-in-window 0..7
    const int csw  = (lane & 7) ^ rsub;      // swizzled global chunk for staging

    float4v acc[IMN][4];
#pragma unroll
    for (int a = 0; a < IMN; a++)
#pragma unroll
        for (int b = 0; b < 4; b++) acc[a][b] = (float4v){0.f, 0.f, 0.f, 0.f};

    auto stage = [&](int buf, int kt) {
        ushort_t* Ad = (ushort_t*)(smem + buf * (ABYTES + BBYTES));
        ushort_t* Bd = (ushort_t*)(smem + buf * (ABYTES + BBYTES) + ABYTES);
        const int kbase = kt * 64 + csw * 8;
#pragma unroll
        for (int t = 0; t < IMN; t++) {          // A: TM rows = IMN windows/wave
            const int w8 = (wid * IMN + t) * 8;
            int rA = min(i0 + w8 + rsub, rowsA - 1);
            gl_lds16(A + (size_t)rA * 256 + kbase, Ad + w8 * 64);
        }
#pragma unroll
        for (int t = 0; t < 4; t++) {            // B: 128 rows = 4 windows/wave
            const int w8 = (wid * 4 + t) * 8;
            int rB = min(j0 + w8 + rsub, rowsB - 1);
            gl_lds16(B + (size_t)rB * 256 + kbase, Bd + w8 * 64);
        }
    };

    stage(0, 0);                                 // prologue
#pragma unroll
    for (int kt = 0; kt < 4; kt++) {
        if (kt < 3) {
            stage((kt + 1) & 1, kt + 1);         // prefetch next tile (other buffer)
            asm volatile("s_waitcnt vmcnt(%0)" :: "n"(NLD) : "memory");  // cur landed
        } else {
            asm volatile("s_waitcnt vmcnt(0)" ::: "memory");
        }
        __builtin_amdgcn_s_barrier();            // all waves: cur tile fully in LDS
        asm volatile("" ::: "memory");           // no ds_read hoists above barrier
        const ushort_t* Ac = (const ushort_t*)(smem + (kt & 1) * (ABYTES + BBYTES));
        const ushort_t* Bc = Ac + ABYTES / 2;    // ushort offset = ABYTES bytes
#pragma unroll
        for (int ks = 0; ks < 2; ks++) {
            const int chb = ks * 4 + quad;
            const int sw = ((chb ^ (r16 & 7))) * 8;
            short8 af[IMN], bfr[4];
#pragma unroll
            for (int im = 0; im < IMN; im++)
                af[im] = *(const short8*)(Ac + (wm * (TM / 2) + im * 16 + r16) * 64 + sw);
#pragma unroll
            for (int jn = 0; jn < 4; jn++)
                bfr[jn] = *(const short8*)(Bc + (wn * 64 + jn * 16 + r16) * 64 + sw);
#pragma unroll
            for (int im = 0; im < IMN; im++)
#pragma unroll
                for (int jn = 0; jn < 4; jn++)
                    acc[im][jn] = __builtin_amdgcn_mfma_f32_16x16x32_bf16(
                        af[im], bfr[jn], acc[im][jn], 0, 0, 0);
        }
        if (kt < 3) {
            // DS queue drain before any wave re-stages this buffer (ISA §8)
            asm volatile("s_waitcnt lgkmcnt(0)" ::: "memory");
            __builtin_amdgcn_sched_barrier(0);
            __builtin_amdgcn_s_barrier();        // reads of cur done -> re-stageable
            asm volatile("" ::: "memory");
        }
    }

    const int rows_lim = rowsA - i0;
    const int cols_lim = rowsB - j0;

    if constexpr (sizeof(TOUT) == 4) {
        // ---- fp32: LDS-transposed epilogue, 32-row chunks, pitch 132 ----
        float* T = (float*)smem;
        constexpr int NCH = TM / 32;
#pragma unroll
        for (int c = 0; c < NCH; c++) {
            const int crow = c * 32;
            __syncthreads();                     // full drain: LDS free for reuse
            if (wm == crow / (TM / 2)) {
                const int imb = (crow - wm * (TM / 2)) / 16;
#pragma unroll
                for (int ii = 0; ii < 2; ii++) {
                    const int im = imb + ii;
#pragma unroll
                    for (int jn = 0; jn < 4; jn++) {
                        const int jl = wn * 64 + jn * 16 + r16;
                        float bj = 0.f;
                        if (!BIAS_I) {
                            int jg = j0 + jl;
                            bj = (jg >= jsplit) ? bias2[jg - jsplit] : bias[jg];
                        }
#pragma unroll
                        for (int r = 0; r < 4; r++) {
                            const int rl = ii * 16 + quad * 4 + r;
                            float bv = BIAS_I ? bias[min(i0 + crow + rl, rowsA - 1)] : bj;
                            T[rl * 132 + jl] = fmaxf(acc[im][jn][r] + bv, 0.f);
                        }
                    }
                }
            }
            __syncthreads();
            const int c4 = tid & 31, rl0 = tid >> 5;
#pragma unroll
            for (int s = 0; s < 4; s++) {
                const int rl = rl0 + s * 8;
                const int il = crow + rl;
                if (il < rows_lim) {
                    const int jl = c4 * 4;
                    float* dst = (float*)C + (size_t)(i0 + il) * rowsB + j0 + jl;
                    if (jl + 4 <= cols_lim) {
                        float4v vv = *(const float4v*)&T[rl * 132 + jl];
                        __builtin_nontemporal_store(vv, (float4v*)dst);
                    } else {
                        for (int jj = 0; jj < 4; jj++)
                            if (jl + jj < cols_lim) dst[jj] = T[rl * 132 + jl + jj];
                    }
                }
            }
        }
    } else {
#pragma unroll
        for (int im = 0; im < IMN; im++) {
#pragma unroll
            for (int jn = 0; jn < 4; jn++) {
                const int jl = wn * 64 + jn * 16 + r16;
                if (jl < cols_lim) {
                    float bj = 0.f;
                    if (!BIAS_I) {
                        int jg = j0 + jl;
                        bj = (jg >= jsplit) ? bias2[jg - jsplit] : bias[jg];
                    }
#pragma unroll
                    for (int r = 0; r < 4; r++) {
                        const int il = wm * (TM / 2) + im * 16 + quad * 4 + r;
                        if (il < rows_lim) {
                            float bv = BIAS_I ? bias[i0 + il] : bj;
                            float v = fmaxf(acc[im][jn][r] + bv, 0.f);
                            stv(C + (size_t)(i0 + il) * rowsB + (j0 + jl), v);
                        }
                    }
                }
            }
        }
    }
}

// ---------------- fused aggregate+GEMM tile body (TM=64) ----------------
// Gather phase: each wave aggregates 16 nodes (same per-node loop as the standalone
// aggregate: lane t owns cols {2t,2t+1} mean and {128+2t,128+2t+1} self), ds_writes
// into Afull in the XOR-swizzled chunk layout the K-loop's ds_read_b128 expects:
//   elem(r, kt, ch, e) at r*256 + kt*64 + (ch ^ (r&7))*8 + e.
// K-loop: A static in LDS, B double-buffered via gl_lds16, counted vmcnt(4),
// R4 race-fixed barrier discipline.
template <typename TIN, typename TOUT>
__device__ __forceinline__ void fused_tile_body(
    char* smem, int pid_m, int pid_n,
    const TIN* __restrict__ act, int su, int ou,
    const int* __restrict__ srcs, const int* __restrict__ rowptr,
    const float* __restrict__ deginv,
    const ushort_t* __restrict__ Bw, const float* __restrict__ bias,
    const float* __restrict__ bias2, int jsplit,
    TOUT* __restrict__ C, int rowsA, int rowsB) {

    ushort_t* Afull = (ushort_t*)smem;              // [64][256] swizzled, 32 KB
    ushort_t* Blds  = (ushort_t*)(smem + 32768);    // 2 x [128][64], 32 KB

    const int i0 = pid_m * 64;
    const int j0 = pid_n * 128;
    const int tid  = threadIdx.x;
    const int lane = tid & 63;
    const int wid  = tid >> 6;
    const int wm = wid >> 1, wn = wid & 1;
    const int r16 = lane & 15, quad = lane >> 4;
    const int rsub = lane >> 3;
    const int csw  = (lane & 7) ^ rsub;
    const int t = lane;

    // ---- gather phase ----
    const int slot_base = (t & 31) >> 2;            // chunk of col-pair 2t within kt
    for (int k = 0; k < 16; k++) {
        const int r = wid * 16 + k;                  // tile row
        const int gnode = min(i0 + r, rowsA - 1);
        int e0 = rowptr[gnode], e1 = rowptr[gnode + 1];
        float ax = 0.f, ay = 0.f;
        int e = e0;
        for (; e + 4 <= e1; e += 4) {
            int s0 = srcs[e], s1 = srcs[e + 1], s2 = srcs[e + 2], s3 = srcs[e + 3];
            float2 v0 = ld2g(act, (size_t)s0, su, ou, t);
            float2 v1 = ld2g(act, (size_t)s1, su, ou, t);
            float2 v2 = ld2g(act, (size_t)s2, su, ou, t);
            float2 v3 = ld2g(act, (size_t)s3, su, ou, t);
            ax += v0.x + v1.x + v2.x + v3.x;
            ay += v0.y + v1.y + v2.y + v3.y;
        }
        for (; e < e1; e++) {
            float2 v = ld2g(act, (size_t)srcs[e], su, ou, t);
            ax += v.x; ay += v.y;
        }
        float dinv = deginv[gnode];
        uint_t m  = ((uint_t)f2bf(ay * dinv) << 16) | (uint_t)f2bf(ax * dinv);
        uint_t sf = self_pack(act, (size_t)gnode, su, ou, t);
        const int slot = slot_base ^ (r & 7);
        const int idx = r * 128 + ((t >> 5) << 5) + (slot << 2) + (t & 3);
        ((uint_t*)Afull)[idx]      = m;              // cols 2t,2t+1   (kt 0/1)
        ((uint_t*)Afull)[idx + 64] = sf;             // cols 128+2t,.. (kt 2/3)
    }
    __syncthreads();                                 // Afull complete (full drain)

    float4v acc[2][4];
#pragma unroll
    for (int a = 0; a < 2; a++)
#pragma unroll
        for (int b = 0; b < 4; b++) acc[a][b] = (float4v){0.f, 0.f, 0.f, 0.f};

    auto stageB = [&](int buf, int kt) {
        ushort_t* Bd = Blds + buf * 8192;
        const int kbase = kt * 64 + csw * 8;
#pragma unroll
        for (int w = 0; w < 4; w++) {                // B: 128 rows = 4 windows/wave
            const int w8 = (wid * 4 + w) * 8;
            int rB = min(j0 + w8 + rsub, rowsB - 1);
            gl_lds16(Bw + (size_t)rB * 256 + kbase, Bd + w8 * 64);
        }
    };

    stageB(0, 0);                                    // prologue (4 VMEM/wave)
#pragma unroll
    for (int kt = 0; kt < 4; kt++) {
        if (kt < 3) {
            stageB((kt + 1) & 1, kt + 1);            // prefetch next (4 more in flight)
            asm volatile("s_waitcnt vmcnt(%0)" :: "n"(4) : "memory");  // cur landed
        } else {
            asm volatile("s_waitcnt vmcnt(0)" ::: "memory");
        }
        __builtin_amdgcn_s_barrier();                // cur B tile fully in LDS
        asm volatile("" ::: "memory");
        const ushort_t* Bc = Blds + (kt & 1) * 8192;
#pragma unroll
        for (int ks = 0; ks < 2; ks++) {
            const int chb = ks * 4 + quad;
            const int sw = ((chb ^ (r16 & 7))) * 8;
            short8 af[2], bfr[4];
#pragma unroll
            for (int im = 0; im < 2; im++)
                af[im] = *(const short8*)(Afull + (wm * 32 + im * 16 + r16) * 256 + kt * 64 + sw);
#pragma unroll
            for (int jn = 0; jn < 4; jn++)
                bfr[jn] = *(const short8*)(Bc + (wn * 64 + jn * 16 + r16) * 64 + sw);
#pragma unroll
            for (int im = 0; im < 2; im++)
#pragma unroll
                for (int jn = 0; jn < 4; jn++)
                    acc[im][jn] = __builtin_amdgcn_mfma_f32_16x16x32_bf16(
                        af[im], bfr[jn], acc[im][jn], 0, 0, 0);
        }
        if (kt < 3) {
            // DS queue drain before any wave re-stages this B buffer (ISA §8)
            asm volatile("s_waitcnt lgkmcnt(0)" ::: "memory");
            __builtin_amdgcn_sched_barrier(0);
            __builtin_amdgcn_s_barrier();
            asm volatile("" ::: "memory");
        }
    }

    const int rows_lim = rowsA - i0;
    const int cols_lim = rowsB - j0;

    if constexpr (sizeof(TOUT) == 4) {
        // ---- fp32: LDS-transposed epilogue (TM=64), pitch 132 ----
        float* T = (float*)smem;
#pragma unroll
        for (int c = 0; c < 2; c++) {
            const int crow = c * 32;
            __syncthreads();
            if (wm == c) {
#pragma unroll
                for (int ii = 0; ii < 2; ii++) {
                    const int im = ii;
#pragma unroll
                    for (int jn = 0; jn < 4; jn++) {
                        const int jl = wn * 64 + jn * 16 + r16;
                        int jg = j0 + jl;
                        float bj = (jg >= jsplit) ? bias2[jg - jsplit] : bias[jg];
#pragma unroll
                        for (int r = 0; r < 4; r++) {
                            const int rl = ii * 16 + quad * 4 + r;
                            T[rl * 132 + jl] = fmaxf(acc[im][jn][r] + bj, 0.f);
                        }
                    }
                }
            }
            __syncthreads();
            const int c4 = tid & 31, rl0 = tid >> 5;
#pragma unroll
            for (int s = 0; s < 4; s++) {
                const int rl = rl0 + s * 8;
                const int il = crow + rl;
                if (il < rows_lim) {
                    const int jl = c4 * 4;
                    float* dst = (float*)C + (size_t)(i0 + il) * rowsB + j0 + jl;
                    if (jl + 4 <= cols_lim) {
                        float4v vv = *(const float4v*)&T[rl * 132 + jl];
                        __builtin_nontemporal_store(vv, (float4v*)dst);
                    } else {
                        for (int jj = 0; jj < 4; jj++)
                            if (jl + jj < cols_lim) dst[jj] = T[rl * 132 + jl + jj];
                    }
                }
            }
        }
    } else {
        // ---- bf16: direct scalar stores ----
#pragma unroll
        for (int im = 0; im < 2; im++) {
#pragma unroll
            for (int jn = 0; jn < 4; jn++) {
                const int jl = wn * 64 + jn * 16 + r16;
                if (jl < cols_lim) {
                    int jg = j0 + jl;
                    float bj = (jg >= jsplit) ? bias2[jg - jsplit] : bias[jg];
#pragma unroll
                    for (int r = 0; r < 4; r++) {
                        const int il = wm * 32 + im * 16 + quad * 4 + r;
                        if (il < rows_lim) {
                            float v = fmaxf(acc[im][jn][r] + bj, 0.f);
                            stv(C + (size_t)(i0 + il) * rowsB + (j0 + jl), v);
                        }
                    }
                }
            }
        }
    }
}

// standalone fused agg+GEMM (bf16 out): grid = tilesM * tilesN
template <typename TIN>
__global__ __launch_bounds__(256) void fused_agg_gemm_kernel(
    const TIN* __restrict__ act, int su, int ou,
    const int* __restrict__ srcs, const int* __restrict__ rowptr,
    const float* __restrict__ deginv,
    const ushort_t* __restrict__ Bw, const float* __restrict__ bias,
    const float* __restrict__ bias2, int jsplit,
    ushort_t* __restrict__ C, int rowsA, int rowsB, int tilesN) {
    __shared__ __align__(16) char smem[65536];
    const int pid_m = blockIdx.x / tilesN;
    const int pid_n = blockIdx.x % tilesN;
    fused_tile_body<TIN, ushort_t>(smem, pid_m, pid_n, act, su, ou, srcs, rowptr,
                                   deginv, Bw, bias, bias2, jsplit, C, rowsA, rowsB);
}

// Dual fp32 dispatch: blocks [0,nA) = fused a2 (gathers hbC a-half itself);
// rest = s2 (TM=128, bias-i, 8x8 supergroup + bijective XCD chunk on local index).
__global__ __launch_bounds__(256) void gemm_dual_kernel(
    const ushort_t* __restrict__ actA, const int* __restrict__ srcs,
    const int* __restrict__ rowptr, const float* __restrict__ deginv,
    const ushort_t* __restrict__ Ba, const float* __restrict__ biasA,
    float* __restrict__ Ca, int nA,
    const ushort_t* __restrict__ As, const ushort_t* __restrict__ Bs,
    const float* __restrict__ biasS, float* __restrict__ Cs,
    int N, int tilesMs) {
    __shared__ __align__(16) char smem[65536];
    const int BIG = 1 << 30;
    if ((int)blockIdx.x < nA) {
        fused_tile_body<ushort_t, float>(smem, blockIdx.x, 0, actA, 128, 0,
                                         srcs, rowptr, deginv, Ba, biasA, nullptr, BIG,
                                         Ca, N, 128);
    } else {
        const int lin = blockIdx.x - nA;
        const int nwg = gridDim.x - nA;            // tM8*tM8*64, multiple of 64
        const int w = (lin & 7) * (nwg >> 3) + (lin >> 3);   // XCD chunk (bijective)
        const int tM8 = (tilesMs + 7) >> 3;
        const int sg = w >> 6, is = w & 63;        // 8x8 supergroup
        const int sgm = sg % tM8, sgn = sg / tM8;
        const int pid_m = sgm * 8 + (is & 7);
        const int pid_n = sgn * 8 + (is >> 3);
        if (pid_m >= tilesMs || pid_n >= tilesMs) return;   // block-uniform exit
        gemm_tile_body<true, 128, float>(smem, pid_m, pid_n, As, Bs, biasS, nullptr, BIG,
                                         Cs, N, N);
    }
}

// ---------------- host launch ----------------
extern "C" void kernel_launch(void* const* d_in, const int* in_sizes, int n_in,
                              void* d_out, int out_size, void* d_ws, size_t ws_size,
                              hipStream_t stream) {
    const int N = in_sizes[18];       // bl_s2 length == num nodes
    const int E = in_sizes[1] / 2;

    const float* x = (const float*)d_in[0];
    const int* ei = (const int*)d_in[1];
    const int* srcv = ei;
    const int* dstv = ei + E;

    // layer order in inputs: e1, e2, a1, a2, s1, s2
    const float* Wl[6] = {(const float*)d_in[2],  (const float*)d_in[5],
                          (const float*)d_in[8],  (const float*)d_in[11],
                          (const float*)d_in[14], (const float*)d_in[17]};
    const float* bl[6] = {(const float*)d_in[3],  (const float*)d_in[6],
                          (const float*)d_in[9],  (const float*)d_in[12],
                          (const float*)d_in[15], (const float*)d_in[18]};
    const float* Wr[6] = {(const float*)d_in[4],  (const float*)d_in[7],
                          (const float*)d_in[10], (const float*)d_in[13],
                          (const float*)d_in[16], (const float*)d_in[19]};

    char* p = (char*)d_ws;
    auto carve = [&](size_t bytes) -> char* {
        char* q = p;
        p += (bytes + 255) & ~(size_t)255;
        return q;
    };
    int*      cnt    = (int*)carve((size_t)N * 4);
    int*      rowptr = (int*)carve((size_t)(N + 1) * 4);
    int*      cursor = (int*)carve((size_t)N * 4);
    float*    deginv = (float*)carve((size_t)N * 4);
    int*      srcs   = (int*)carve((size_t)E * 4);
    ushort_t* AcatS  = (ushort_t*)carve((size_t)N * 256 * 2);
    ushort_t* hbA    = (ushort_t*)carve((size_t)N * 128 * 2);   // bf16 activations
    ushort_t* hbB    = (ushort_t*)carve((size_t)N * 128 * 2);
    ushort_t* hbC    = (ushort_t*)carve((size_t)N * 256 * 2);   // a1|s1 fused output
    ushort_t* WTs2   = (ushort_t*)carve((size_t)N * 256 * 2);   // s2 weights transposed
    ushort_t* WsT    = (ushort_t*)carve((size_t)5 * 128 * 256 * 2);

    hipMemsetAsync(cnt, 0, (size_t)N * 4, stream);

    // fused setup: w5 transposes (40 tiles) + ws2 transpose (nbx*4) + hist
    W5 w5;
    w5.W0[0] = Wl[0]; w5.W1[0] = Wr[0];   // e1
    w5.W0[1] = Wl[1]; w5.W1[1] = Wr[1];   // e2
    w5.W0[2] = Wl[2]; w5.W1[2] = Wr[2];   // a1
    w5.W0[3] = Wl[4]; w5.W1[3] = Wr[4];   // s1
    w5.W0[4] = Wl[3]; w5.W1[4] = Wr[3];   // a2
    const int nbx = (N + 63) / 64;
    const int histBlocks = (E + 255) / 256;
    setup_kernel<<<40 + nbx * 4 + histBlocks, 256, 0, stream>>>(
        w5, WsT, Wl[5], Wr[5], WTs2, N, nbx, dstv, cnt, E);
    scan_kernel<<<1, 1024, 0, stream>>>(cnt, rowptr, cursor, deginv, N);
    scatter_kernel<<<(E + 255) / 256, 256, 0, stream>>>(srcv, dstv, cursor, srcs, E);

    float* outp = (float*)d_out;
    float* xh_out = outp + (size_t)N * N;

    const int tM128 = (N + 127) / 128;    // 79  (s2 tiles)
    const int tM64  = (N + 63) / 64;      // 157 (small-GEMM tiles)
    const int BIG = 1 << 30;

    // e1: gather x (fp32, stride 64 float2) + GEMM -> hbA
    fused_agg_gemm_kernel<float><<<tM64, 256, 0, stream>>>(
        x, 64, 0, srcs, rowptr, deginv, WsT + 0 * 32768, bl[0], nullptr, BIG,
        hbA, N, 128, 1);
    // e2: gather hbA + GEMM -> hbB (h)
    fused_agg_gemm_kernel<ushort_t><<<tM64, 256, 0, stream>>>(
        hbA, 64, 0, srcs, rowptr, deginv, WsT + 1 * 32768, bl[1], nullptr, BIG,
        hbB, N, 128, 1);
    // a1+s1: gather hbB + 256-col GEMM -> hbC (gather duplicated across pid_n, L2-hot)
    fused_agg_gemm_kernel<ushort_t><<<tM64 * 2, 256, 0, stream>>>(
        hbB, 64, 0, srcs, rowptr, deginv, WsT + 2 * 32768, bl[2], bl[4], 128,
        hbC, N, 256, 2);
    // s-half aggregate of hbC -> AcatS (s2's B operand; each panel read by ~79 blocks)
    aggS_kernel<<<(N + 3) / 4, 256, 0, stream>>>(hbC, srcs, rowptr, deginv, AcatS, N);
    // dual: a2 (fused gather of hbC a-half) -> xh, s2 -> outp
    const int tM8 = (tM128 + 7) / 8;
    gemm_dual_kernel<<<tM64 + tM8 * tM8 * 64, 256, 0, stream>>>(
        hbC, srcs, rowptr, deginv, WsT + 4 * 32768, bl[3], xh_out, tM64,
        WTs2, AcatS, bl[5], outp, N, tM128);

    (void)n_in; (void)out_size; (void)ws_size;
}